// Round 1
// baseline (263.394 us; speedup 1.0000x reference)
//
#include <hip/hip_runtime.h>

#define D_FEAT 256

// One block (256 threads = 4 waves) per batch node.
// Wave w accumulates edges start+w, start+w+4, ... ; each lane holds float4
// (64 lanes x 4 floats = 256 dims). Cross-wave reduce through LDS.
__global__ __launch_bounds__(256) void intra_agg_kernel(
    const float* __restrict__ features,    // [N_NODES, 256]
    const int*   __restrict__ neigh_idx,   // [E]
    const int*   __restrict__ segment_ids, // [E], sorted ascending
    const float* __restrict__ self_feats,  // [B, 256]
    float*       __restrict__ out,         // [B, 512]
    int E)
{
    const int b    = blockIdx.x;
    const int tid  = threadIdx.x;
    const int wave = tid >> 6;   // 0..3
    const int lane = tid & 63;   // 0..63

    __shared__ int   s_range[2];
    __shared__ float s_part[3][D_FEAT];  // partials from waves 1..3

    if (tid == 0) {
        // lower_bound(segment_ids, b)
        int lo = 0, hi = E;
        while (lo < hi) {
            int mid = (lo + hi) >> 1;
            if (segment_ids[mid] < b) lo = mid + 1; else hi = mid;
        }
        s_range[0] = lo;
        // lower_bound(segment_ids, b+1), starting from lo
        hi = E;
        while (lo < hi) {
            int mid = (lo + hi) >> 1;
            if (segment_ids[mid] < b + 1) lo = mid + 1; else hi = mid;
        }
        s_range[1] = lo;
    }
    __syncthreads();

    const int start = s_range[0];
    const int end   = s_range[1];
    const int count = end - start;

    float4 acc = make_float4(0.f, 0.f, 0.f, 0.f);
    for (int e = start + wave; e < end; e += 4) {
        const int node = neigh_idx[e];
        const float4* row = (const float4*)(features + (long long)node * D_FEAT);
        float4 v = row[lane];           // coalesced: 64 lanes x 16B = 1KB row
        acc.x += v.x; acc.y += v.y; acc.z += v.z; acc.w += v.w;
    }

    if (wave > 0) {
        ((float4*)s_part[wave - 1])[lane] = acc;
    }
    __syncthreads();

    if (wave == 0) {
        float4 a1 = ((const float4*)s_part[0])[lane];
        float4 a2 = ((const float4*)s_part[1])[lane];
        float4 a3 = ((const float4*)s_part[2])[lane];
        acc.x += a1.x + a2.x + a3.x;
        acc.y += a1.y + a2.y + a3.y;
        acc.z += a1.z + a2.z + a3.z;
        acc.w += a1.w + a2.w + a3.w;

        const float inv = 1.0f / fmaxf((float)count, 1.0f);
        float4 agg;
        agg.x = acc.x * inv; agg.y = acc.y * inv;
        agg.z = acc.z * inv; agg.w = acc.w * inv;

        const float4 self = ((const float4*)(self_feats + (long long)b * D_FEAT))[lane];
        float4 diff;
        diff.x = self.x - agg.x; diff.y = self.y - agg.y;
        diff.z = self.z - agg.z; diff.w = self.w - agg.w;

        float4* o = (float4*)(out + (long long)b * 2 * D_FEAT);
        o[lane]      = diff;   // out[b, 0:256]
        o[64 + lane] = agg;    // out[b, 256:512]
    }
}

extern "C" void kernel_launch(void* const* d_in, const int* in_sizes, int n_in,
                              void* d_out, int out_size, void* d_ws, size_t ws_size,
                              hipStream_t stream) {
    const float* features    = (const float*)d_in[0];
    const int*   neigh_idx   = (const int*)d_in[1];
    const int*   segment_ids = (const int*)d_in[2];
    const float* self_feats  = (const float*)d_in[3];
    float*       out         = (float*)d_out;

    const int E = in_sizes[1];                 // 524288
    const int B = in_sizes[3] / D_FEAT;        // 16384

    intra_agg_kernel<<<B, 256, 0, stream>>>(features, neigh_idx, segment_ids,
                                            self_feats, out, E);
}

// Round 2
// 230.538 us; speedup vs baseline: 1.1425x; 1.1425x over previous
//
#include <hip/hip_runtime.h>

#define D_FEAT 256

// Kernel A: CSR offsets via parallel binary search.
// offs[b] = lower_bound(segment_ids, b) for b in [0, B].
__global__ __launch_bounds__(256) void seg_offsets_kernel(
    const int* __restrict__ seg, int* __restrict__ offs, int E, int B)
{
    int b = blockIdx.x * blockDim.x + threadIdx.x;
    if (b > B) return;
    int lo = 0, hi = E;
    while (lo < hi) {
        int mid = (lo + hi) >> 1;
        if (seg[mid] < b) lo = mid + 1; else hi = mid;
    }
    offs[b] = lo;
}

// Kernel B: one wave (64 lanes) per segment. Each lane holds float4 ->
// 64*4 = 256 dims. Unroll x8: 8 independent 1KB row loads in flight.
__global__ __launch_bounds__(256) void intra_agg_main(
    const float* __restrict__ features,   // [N_NODES, 256]
    const int*   __restrict__ neigh,      // [E]
    const int*   __restrict__ offs,       // [B+1]
    const float* __restrict__ self_feats, // [B, 256]
    float*       __restrict__ out,        // [B, 512]
    int B)
{
    const int s    = blockIdx.x * 4 + (threadIdx.x >> 6);
    const int lane = threadIdx.x & 63;
    if (s >= B) return;

    const int start = offs[s];
    const int end   = offs[s + 1];
    const int count = end - start;

    float4 a0 = make_float4(0.f, 0.f, 0.f, 0.f);
    float4 a1 = make_float4(0.f, 0.f, 0.f, 0.f);
    float4 a2 = make_float4(0.f, 0.f, 0.f, 0.f);
    float4 a3 = make_float4(0.f, 0.f, 0.f, 0.f);

    int e = start;
    for (; e + 8 <= end; e += 8) {
        // 8 uniform index loads (L2-hot), then 8 independent row loads.
        int n0 = neigh[e + 0], n1 = neigh[e + 1], n2 = neigh[e + 2], n3 = neigh[e + 3];
        int n4 = neigh[e + 4], n5 = neigh[e + 5], n6 = neigh[e + 6], n7 = neigh[e + 7];
        float4 v0 = ((const float4*)(features + (size_t)n0 * D_FEAT))[lane];
        float4 v1 = ((const float4*)(features + (size_t)n1 * D_FEAT))[lane];
        float4 v2 = ((const float4*)(features + (size_t)n2 * D_FEAT))[lane];
        float4 v3 = ((const float4*)(features + (size_t)n3 * D_FEAT))[lane];
        float4 v4 = ((const float4*)(features + (size_t)n4 * D_FEAT))[lane];
        float4 v5 = ((const float4*)(features + (size_t)n5 * D_FEAT))[lane];
        float4 v6 = ((const float4*)(features + (size_t)n6 * D_FEAT))[lane];
        float4 v7 = ((const float4*)(features + (size_t)n7 * D_FEAT))[lane];
        a0.x += v0.x; a0.y += v0.y; a0.z += v0.z; a0.w += v0.w;
        a1.x += v1.x; a1.y += v1.y; a1.z += v1.z; a1.w += v1.w;
        a2.x += v2.x; a2.y += v2.y; a2.z += v2.z; a2.w += v2.w;
        a3.x += v3.x; a3.y += v3.y; a3.z += v3.z; a3.w += v3.w;
        a0.x += v4.x; a0.y += v4.y; a0.z += v4.z; a0.w += v4.w;
        a1.x += v5.x; a1.y += v5.y; a1.z += v5.z; a1.w += v5.w;
        a2.x += v6.x; a2.y += v6.y; a2.z += v6.z; a2.w += v6.w;
        a3.x += v7.x; a3.y += v7.y; a3.z += v7.z; a3.w += v7.w;
    }
    for (; e < end; ++e) {
        int n = neigh[e];
        float4 v = ((const float4*)(features + (size_t)n * D_FEAT))[lane];
        a0.x += v.x; a0.y += v.y; a0.z += v.z; a0.w += v.w;
    }

    float4 acc;
    acc.x = (a0.x + a1.x) + (a2.x + a3.x);
    acc.y = (a0.y + a1.y) + (a2.y + a3.y);
    acc.z = (a0.z + a1.z) + (a2.z + a3.z);
    acc.w = (a0.w + a1.w) + (a2.w + a3.w);

    const float inv = 1.0f / fmaxf((float)count, 1.0f);
    float4 agg;
    agg.x = acc.x * inv; agg.y = acc.y * inv;
    agg.z = acc.z * inv; agg.w = acc.w * inv;

    const float4 self = ((const float4*)(self_feats + (size_t)s * D_FEAT))[lane];
    float4 diff;
    diff.x = self.x - agg.x; diff.y = self.y - agg.y;
    diff.z = self.z - agg.z; diff.w = self.w - agg.w;

    float4* o = (float4*)(out + (size_t)s * 2 * D_FEAT);
    o[lane]      = diff;   // out[s, 0:256]
    o[64 + lane] = agg;    // out[s, 256:512]
}

extern "C" void kernel_launch(void* const* d_in, const int* in_sizes, int n_in,
                              void* d_out, int out_size, void* d_ws, size_t ws_size,
                              hipStream_t stream) {
    const float* features    = (const float*)d_in[0];
    const int*   neigh_idx   = (const int*)d_in[1];
    const int*   segment_ids = (const int*)d_in[2];
    const float* self_feats  = (const float*)d_in[3];
    float*       out         = (float*)d_out;

    const int E = in_sizes[1];                 // 524288
    const int B = in_sizes[3] / D_FEAT;        // 16384

    int* offs = (int*)d_ws;                    // (B+1) ints

    seg_offsets_kernel<<<(B + 1 + 255) / 256, 256, 0, stream>>>(
        segment_ids, offs, E, B);

    intra_agg_main<<<(B + 3) / 4, 256, 0, stream>>>(
        features, neigh_idx, offs, self_feats, out, B);
}

// Round 3
// 221.459 us; speedup vs baseline: 1.1894x; 1.0410x over previous
//
#include <hip/hip_runtime.h>

#define D_FEAT 256

__device__ __forceinline__ unsigned short f2bf_rn(float f) {
    unsigned int u = __float_as_uint(f);
    u += 0x7FFFu + ((u >> 16) & 1u);     // round-to-nearest-even
    return (unsigned short)(u >> 16);
}

// ---------------- Pass 1 (fused): features fp32->bf16 + CSR offsets ----------
__global__ __launch_bounds__(256) void prep_kernel(
    const float* __restrict__ features,        // [N*D] fp32
    const int*   __restrict__ seg,             // [E] sorted
    unsigned short* __restrict__ fbf,          // [N*D] bf16 bits
    int*         __restrict__ offs,            // [B+1]
    long long n4,                              // N*D/4
    int E, int B, int convBlocks)
{
    if ((int)blockIdx.x < convBlocks) {
        long long i = (long long)blockIdx.x * 256 + threadIdx.x;
        const long long stride = (long long)convBlocks * 256;
        const float4* src = (const float4*)features;
        ushort4* dst = (ushort4*)fbf;
        for (; i < n4; i += stride) {
            float4 v = src[i];
            ushort4 o;
            o.x = f2bf_rn(v.x); o.y = f2bf_rn(v.y);
            o.z = f2bf_rn(v.z); o.w = f2bf_rn(v.w);
            dst[i] = o;
        }
    } else {
        int b = ((int)blockIdx.x - convBlocks) * 256 + threadIdx.x;
        if (b <= B) {
            int lo = 0, hi = E;
            while (lo < hi) {
                int mid = (lo + hi) >> 1;
                if (seg[mid] < b) lo = mid + 1; else hi = mid;
            }
            offs[b] = lo;
        }
    }
}

// ---------------- Pass 2: one wave per segment, bf16 gather ------------------
// Lane covers dims [4*lane, 4*lane+4): one uint2 (4 bf16 = 8B) per row.
// Unroll x8 keeps 8 independent 512B row-loads in flight per wave.
__global__ __launch_bounds__(256) void intra_agg_bf16(
    const unsigned short* __restrict__ fbf,    // [N, 256] bf16
    const int*   __restrict__ neigh,           // [E]
    const int*   __restrict__ offs,            // [B+1]
    const float* __restrict__ self_feats,      // [B, 256]
    float*       __restrict__ out,             // [B, 512]
    int B)
{
    const int s    = blockIdx.x * 4 + (threadIdx.x >> 6);
    const int lane = threadIdx.x & 63;
    if (s >= B) return;

    const int start = __builtin_amdgcn_readfirstlane(offs[s]);
    const int end   = __builtin_amdgcn_readfirstlane(offs[s + 1]);
    const int count = end - start;

    float a0 = 0.f, a1 = 0.f, a2 = 0.f, a3 = 0.f;
    float c0 = 0.f, c1 = 0.f, c2 = 0.f, c3 = 0.f;

    int e = start;
    for (; e + 8 <= end; e += 8) {
        int n[8];
        #pragma unroll
        for (int i = 0; i < 8; ++i) n[i] = neigh[e + i];
        uint2 v[8];
        #pragma unroll
        for (int i = 0; i < 8; ++i)
            v[i] = *(const uint2*)(fbf + (size_t)n[i] * D_FEAT + (lane << 2));
        #pragma unroll
        for (int i = 0; i < 8; i += 2) {
            a0 += __uint_as_float(v[i].x << 16);
            a1 += __uint_as_float(v[i].x & 0xFFFF0000u);
            a2 += __uint_as_float(v[i].y << 16);
            a3 += __uint_as_float(v[i].y & 0xFFFF0000u);
            c0 += __uint_as_float(v[i + 1].x << 16);
            c1 += __uint_as_float(v[i + 1].x & 0xFFFF0000u);
            c2 += __uint_as_float(v[i + 1].y << 16);
            c3 += __uint_as_float(v[i + 1].y & 0xFFFF0000u);
        }
    }
    for (; e < end; ++e) {
        int n = neigh[e];
        uint2 v = *(const uint2*)(fbf + (size_t)n * D_FEAT + (lane << 2));
        a0 += __uint_as_float(v.x << 16);
        a1 += __uint_as_float(v.x & 0xFFFF0000u);
        a2 += __uint_as_float(v.y << 16);
        a3 += __uint_as_float(v.y & 0xFFFF0000u);
    }
    a0 += c0; a1 += c1; a2 += c2; a3 += c3;

    const float inv = 1.0f / fmaxf((float)count, 1.0f);
    float4 agg;
    agg.x = a0 * inv; agg.y = a1 * inv; agg.z = a2 * inv; agg.w = a3 * inv;

    const float4 self = ((const float4*)(self_feats + (size_t)s * D_FEAT))[lane];
    float4 diff;
    diff.x = self.x - agg.x; diff.y = self.y - agg.y;
    diff.z = self.z - agg.z; diff.w = self.w - agg.w;

    float4* o = (float4*)(out + (size_t)s * 2 * D_FEAT);
    o[lane]      = diff;   // out[s, 0:256]
    o[64 + lane] = agg;    // out[s, 256:512]
}

// ---------------- Fallback fp32 path (if ws too small for bf16 copy) ---------
__global__ __launch_bounds__(256) void seg_offsets_kernel(
    const int* __restrict__ seg, int* __restrict__ offs, int E, int B)
{
    int b = blockIdx.x * blockDim.x + threadIdx.x;
    if (b > B) return;
    int lo = 0, hi = E;
    while (lo < hi) {
        int mid = (lo + hi) >> 1;
        if (seg[mid] < b) lo = mid + 1; else hi = mid;
    }
    offs[b] = lo;
}

__global__ __launch_bounds__(256) void intra_agg_main(
    const float* __restrict__ features,
    const int*   __restrict__ neigh,
    const int*   __restrict__ offs,
    const float* __restrict__ self_feats,
    float*       __restrict__ out,
    int B)
{
    const int s    = blockIdx.x * 4 + (threadIdx.x >> 6);
    const int lane = threadIdx.x & 63;
    if (s >= B) return;

    const int start = offs[s];
    const int end   = offs[s + 1];
    const int count = end - start;

    float4 a0 = make_float4(0.f,0.f,0.f,0.f);
    float4 a1 = make_float4(0.f,0.f,0.f,0.f);
    int e = start;
    for (; e + 2 <= end; e += 2) {
        int n0 = neigh[e], n1 = neigh[e + 1];
        float4 v0 = ((const float4*)(features + (size_t)n0 * D_FEAT))[lane];
        float4 v1 = ((const float4*)(features + (size_t)n1 * D_FEAT))[lane];
        a0.x += v0.x; a0.y += v0.y; a0.z += v0.z; a0.w += v0.w;
        a1.x += v1.x; a1.y += v1.y; a1.z += v1.z; a1.w += v1.w;
    }
    for (; e < end; ++e) {
        int n = neigh[e];
        float4 v = ((const float4*)(features + (size_t)n * D_FEAT))[lane];
        a0.x += v.x; a0.y += v.y; a0.z += v.z; a0.w += v.w;
    }
    a0.x += a1.x; a0.y += a1.y; a0.z += a1.z; a0.w += a1.w;

    const float inv = 1.0f / fmaxf((float)count, 1.0f);
    float4 agg;
    agg.x = a0.x * inv; agg.y = a0.y * inv; agg.z = a0.z * inv; agg.w = a0.w * inv;
    const float4 self = ((const float4*)(self_feats + (size_t)s * D_FEAT))[lane];
    float4 diff;
    diff.x = self.x - agg.x; diff.y = self.y - agg.y;
    diff.z = self.z - agg.z; diff.w = self.w - agg.w;
    float4* o = (float4*)(out + (size_t)s * 2 * D_FEAT);
    o[lane]      = diff;
    o[64 + lane] = agg;
}

extern "C" void kernel_launch(void* const* d_in, const int* in_sizes, int n_in,
                              void* d_out, int out_size, void* d_ws, size_t ws_size,
                              hipStream_t stream) {
    const float* features    = (const float*)d_in[0];
    const int*   neigh_idx   = (const int*)d_in[1];
    const int*   segment_ids = (const int*)d_in[2];
    const float* self_feats  = (const float*)d_in[3];
    float*       out         = (float*)d_out;

    const int E = in_sizes[1];                    // 524288
    const int B = in_sizes[3] / D_FEAT;           // 16384
    const long long NF = (long long)in_sizes[0];  // N*D = 25,600,000

    const size_t offs_bytes = (((size_t)(B + 2) * 4) + 255) & ~(size_t)255;
    const size_t need = offs_bytes + (size_t)NF * 2;

    int* offs = (int*)d_ws;

    if (ws_size >= need) {
        unsigned short* fbf = (unsigned short*)((char*)d_ws + offs_bytes);
        const int convBlocks = 4096;
        const int offsBlocks = (B + 1 + 255) / 256;
        prep_kernel<<<convBlocks + offsBlocks, 256, 0, stream>>>(
            features, segment_ids, fbf, offs, NF / 4, E, B, convBlocks);
        intra_agg_bf16<<<(B + 3) / 4, 256, 0, stream>>>(
            fbf, neigh_idx, offs, self_feats, out, B);
    } else {
        seg_offsets_kernel<<<(B + 1 + 255) / 256, 256, 0, stream>>>(
            segment_ids, offs, E, B);
        intra_agg_main<<<(B + 3) / 4, 256, 0, stream>>>(
            features, neigh_idx, offs, self_feats, out, B);
    }
}

// Round 4
// 216.809 us; speedup vs baseline: 1.2149x; 1.0214x over previous
//
#include <hip/hip_runtime.h>

#define D_FEAT 256

typedef float  f32x4 __attribute__((ext_vector_type(4)));
typedef unsigned int u32x4 __attribute__((ext_vector_type(4)));

__device__ __forceinline__ unsigned short f2bf_rn(float f) {
    unsigned int u = __float_as_uint(f);
    u += 0x7FFFu + ((u >> 16) & 1u);     // round-to-nearest-even
    return (unsigned short)(u >> 16);
}

// ---------------- Pass 1 (fused): features fp32->bf16 + CSR offsets ----------
// fp32 reads are non-temporal (read-once) so they don't evict fbf from L3.
__global__ __launch_bounds__(256) void prep_kernel(
    const float* __restrict__ features,        // [N*D] fp32
    const int*   __restrict__ seg,             // [E] sorted
    unsigned short* __restrict__ fbf,          // [N*D] bf16 bits
    int*         __restrict__ offs,            // [B+1]
    long long n4,                              // N*D/4
    int E, int B, int convBlocks)
{
    if ((int)blockIdx.x < convBlocks) {
        long long i = (long long)blockIdx.x * 256 + threadIdx.x;
        const long long stride = (long long)convBlocks * 256;
        const f32x4* src = (const f32x4*)features;
        ushort4* dst = (ushort4*)fbf;
        for (; i < n4; i += stride) {
            f32x4 v = __builtin_nontemporal_load(src + i);
            ushort4 o;
            o.x = f2bf_rn(v.x); o.y = f2bf_rn(v.y);
            o.z = f2bf_rn(v.z); o.w = f2bf_rn(v.w);
            dst[i] = o;
        }
    } else {
        int b = ((int)blockIdx.x - convBlocks) * 256 + threadIdx.x;
        if (b <= B) {
            int lo = 0, hi = E;
            while (lo < hi) {
                int mid = (lo + hi) >> 1;
                if (seg[mid] < b) lo = mid + 1; else hi = mid;
            }
            offs[b] = lo;
        }
    }
}

// ---------------- Pass 2: one wave per segment, 2 rows per load --------------
// Half-wave (32 lanes x 16B = 512B) covers one bf16 row; the two halves of a
// wave load two different edges with a single dwordx4 per lane. Unroll x4
// pairs -> 8 edges / iter, 8KB in flight per wave. Cross-half reduce via
// __shfl_xor(32) at the end.
__global__ __launch_bounds__(256) void intra_agg_bf16(
    const unsigned short* __restrict__ fbf,    // [N, 256] bf16
    const int*   __restrict__ neigh,           // [E]
    const int*   __restrict__ offs,            // [B+1]
    const float* __restrict__ self_feats,      // [B, 256]
    float*       __restrict__ out,             // [B, 512]
    int B)
{
    const int s    = blockIdx.x * 4 + (threadIdx.x >> 6);
    const int lane = threadIdx.x & 63;
    const int half = lane >> 5;                // 0 or 1: which edge of the pair
    const int hl   = lane & 31;                // position within the row
    if (s >= B) return;

    const int start = __builtin_amdgcn_readfirstlane(offs[s]);
    const int end   = __builtin_amdgcn_readfirstlane(offs[s + 1]);
    const int count = end - start;

    float acc[8];
    #pragma unroll
    for (int k = 0; k < 8; ++k) acc[k] = 0.f;

    const int elem = hl << 3;                  // dim offset: 8 bf16 per lane

    int e = start;
    for (; e + 8 <= end; e += 8) {
        int n0 = neigh[e + 0 + half];
        int n1 = neigh[e + 2 + half];
        int n2 = neigh[e + 4 + half];
        int n3 = neigh[e + 6 + half];
        u32x4 v0 = *(const u32x4*)(fbf + (size_t)n0 * D_FEAT + elem);
        u32x4 v1 = *(const u32x4*)(fbf + (size_t)n1 * D_FEAT + elem);
        u32x4 v2 = *(const u32x4*)(fbf + (size_t)n2 * D_FEAT + elem);
        u32x4 v3 = *(const u32x4*)(fbf + (size_t)n3 * D_FEAT + elem);
        u32x4 vs[4] = {v0, v1, v2, v3};
        #pragma unroll
        for (int i = 0; i < 4; ++i) {
            acc[0] += __uint_as_float(vs[i].x << 16);
            acc[1] += __uint_as_float(vs[i].x & 0xFFFF0000u);
            acc[2] += __uint_as_float(vs[i].y << 16);
            acc[3] += __uint_as_float(vs[i].y & 0xFFFF0000u);
            acc[4] += __uint_as_float(vs[i].z << 16);
            acc[5] += __uint_as_float(vs[i].z & 0xFFFF0000u);
            acc[6] += __uint_as_float(vs[i].w << 16);
            acc[7] += __uint_as_float(vs[i].w & 0xFFFF0000u);
        }
    }
    for (; e + 2 <= end; e += 2) {
        int n = neigh[e + half];
        u32x4 v = *(const u32x4*)(fbf + (size_t)n * D_FEAT + elem);
        acc[0] += __uint_as_float(v.x << 16);
        acc[1] += __uint_as_float(v.x & 0xFFFF0000u);
        acc[2] += __uint_as_float(v.y << 16);
        acc[3] += __uint_as_float(v.y & 0xFFFF0000u);
        acc[4] += __uint_as_float(v.z << 16);
        acc[5] += __uint_as_float(v.z & 0xFFFF0000u);
        acc[6] += __uint_as_float(v.w << 16);
        acc[7] += __uint_as_float(v.w & 0xFFFF0000u);
    }
    if (e < end && half == 0) {                // odd tail: half 0 only
        int n = neigh[e];
        u32x4 v = *(const u32x4*)(fbf + (size_t)n * D_FEAT + elem);
        acc[0] += __uint_as_float(v.x << 16);
        acc[1] += __uint_as_float(v.x & 0xFFFF0000u);
        acc[2] += __uint_as_float(v.y << 16);
        acc[3] += __uint_as_float(v.y & 0xFFFF0000u);
        acc[4] += __uint_as_float(v.z << 16);
        acc[5] += __uint_as_float(v.z & 0xFFFF0000u);
        acc[6] += __uint_as_float(v.w << 16);
        acc[7] += __uint_as_float(v.w & 0xFFFF0000u);
    }

    // combine the two halves: lanes l and l^32 hold the same dims
    #pragma unroll
    for (int k = 0; k < 8; ++k)
        acc[k] += __shfl_xor(acc[k], 32, 64);

    if (half == 0) {                           // lanes 0..31 write 8 dims each
        const float inv = 1.0f / fmaxf((float)count, 1.0f);
        const f32x4* selfp = (const f32x4*)(self_feats + (size_t)s * D_FEAT + elem);
        f32x4 s0 = selfp[0];
        f32x4 s1 = selfp[1];
        f32x4 g0 = { acc[0] * inv, acc[1] * inv, acc[2] * inv, acc[3] * inv };
        f32x4 g1 = { acc[4] * inv, acc[5] * inv, acc[6] * inv, acc[7] * inv };
        f32x4 d0 = { s0.x - g0.x, s0.y - g0.y, s0.z - g0.z, s0.w - g0.w };
        f32x4 d1 = { s1.x - g1.x, s1.y - g1.y, s1.z - g1.z, s1.w - g1.w };

        float* ob = out + (size_t)s * 2 * D_FEAT;
        __builtin_nontemporal_store(d0, (f32x4*)(ob + elem));
        __builtin_nontemporal_store(d1, (f32x4*)(ob + elem + 4));
        __builtin_nontemporal_store(g0, (f32x4*)(ob + D_FEAT + elem));
        __builtin_nontemporal_store(g1, (f32x4*)(ob + D_FEAT + elem + 4));
    }
}

// ---------------- Fallback fp32 path (if ws too small for bf16 copy) ---------
__global__ __launch_bounds__(256) void seg_offsets_kernel(
    const int* __restrict__ seg, int* __restrict__ offs, int E, int B)
{
    int b = blockIdx.x * blockDim.x + threadIdx.x;
    if (b > B) return;
    int lo = 0, hi = E;
    while (lo < hi) {
        int mid = (lo + hi) >> 1;
        if (seg[mid] < b) lo = mid + 1; else hi = mid;
    }
    offs[b] = lo;
}

__global__ __launch_bounds__(256) void intra_agg_main(
    const float* __restrict__ features,
    const int*   __restrict__ neigh,
    const int*   __restrict__ offs,
    const float* __restrict__ self_feats,
    float*       __restrict__ out,
    int B)
{
    const int s    = blockIdx.x * 4 + (threadIdx.x >> 6);
    const int lane = threadIdx.x & 63;
    if (s >= B) return;

    const int start = offs[s];
    const int end   = offs[s + 1];
    const int count = end - start;

    float4 a0 = make_float4(0.f,0.f,0.f,0.f);
    float4 a1 = make_float4(0.f,0.f,0.f,0.f);
    int e = start;
    for (; e + 2 <= end; e += 2) {
        int n0 = neigh[e], n1 = neigh[e + 1];
        float4 v0 = ((const float4*)(features + (size_t)n0 * D_FEAT))[lane];
        float4 v1 = ((const float4*)(features + (size_t)n1 * D_FEAT))[lane];
        a0.x += v0.x; a0.y += v0.y; a0.z += v0.z; a0.w += v0.w;
        a1.x += v1.x; a1.y += v1.y; a1.z += v1.z; a1.w += v1.w;
    }
    for (; e < end; ++e) {
        int n = neigh[e];
        float4 v = ((const float4*)(features + (size_t)n * D_FEAT))[lane];
        a0.x += v.x; a0.y += v.y; a0.z += v.z; a0.w += v.w;
    }
    a0.x += a1.x; a0.y += a1.y; a0.z += a1.z; a0.w += a1.w;

    const float inv = 1.0f / fmaxf((float)count, 1.0f);
    float4 agg;
    agg.x = a0.x * inv; agg.y = a0.y * inv; agg.z = a0.z * inv; agg.w = a0.w * inv;
    const float4 self = ((const float4*)(self_feats + (size_t)s * D_FEAT))[lane];
    float4 diff;
    diff.x = self.x - agg.x; diff.y = self.y - agg.y;
    diff.z = self.z - agg.z; diff.w = self.w - agg.w;
    float4* o = (float4*)(out + (size_t)s * 2 * D_FEAT);
    o[lane]      = diff;
    o[64 + lane] = agg;
}

extern "C" void kernel_launch(void* const* d_in, const int* in_sizes, int n_in,
                              void* d_out, int out_size, void* d_ws, size_t ws_size,
                              hipStream_t stream) {
    const float* features    = (const float*)d_in[0];
    const int*   neigh_idx   = (const int*)d_in[1];
    const int*   segment_ids = (const int*)d_in[2];
    const float* self_feats  = (const float*)d_in[3];
    float*       out         = (float*)d_out;

    const int E = in_sizes[1];                    // 524288
    const int B = in_sizes[3] / D_FEAT;           // 16384
    const long long NF = (long long)in_sizes[0];  // N*D = 25,600,000

    const size_t offs_bytes = (((size_t)(B + 2) * 4) + 255) & ~(size_t)255;
    const size_t need = offs_bytes + (size_t)NF * 2;

    int* offs = (int*)d_ws;

    if (ws_size >= need) {
        unsigned short* fbf = (unsigned short*)((char*)d_ws + offs_bytes);
        const int convBlocks = 4096;
        const int offsBlocks = (B + 1 + 255) / 256;
        prep_kernel<<<convBlocks + offsBlocks, 256, 0, stream>>>(
            features, segment_ids, fbf, offs, NF / 4, E, B, convBlocks);
        intra_agg_bf16<<<(B + 3) / 4, 256, 0, stream>>>(
            fbf, neigh_idx, offs, self_feats, out, B);
    } else {
        seg_offsets_kernel<<<(B + 1 + 255) / 256, 256, 0, stream>>>(
            segment_ids, offs, E, B);
        intra_agg_main<<<(B + 3) / 4, 256, 0, stream>>>(
            features, neigh_idx, offs, self_feats, out, B);
    }
}